// Round 6
// baseline (89.354 us; speedup 1.0000x reference)
//
#include <hip/hip_runtime.h>
#include <hip/hip_bf16.h>
#include <stdint.h>

#define B_ 4
#define M_ 4096
#define N_ 4096
#define D_ 256

typedef __attribute__((ext_vector_type(8))) short bf16x8;
typedef __attribute__((ext_vector_type(4))) float f32x4;

#define AS1 __attribute__((address_space(1)))
#define AS3 __attribute__((address_space(3)))

// RNE float->bf16 (no NaN in this data)
__device__ inline unsigned short f2bf(float f) {
    unsigned int u = __float_as_uint(f);
    return (unsigned short)((u + 0x7fffu + ((u >> 16) & 1u)) >> 16);
}

// One wave per row: compute 1/||row||, scale, convert to bf16.
__global__ __launch_bounds__(256) void norm_cvt(const float* __restrict__ x,
                                                const float* __restrict__ y,
                                                ushort* __restrict__ xb,
                                                ushort* __restrict__ yb) {
    int gw   = (blockIdx.x * 256 + threadIdx.x) >> 6;
    int lane = threadIdx.x & 63;
    const int R = B_ * 4096;
    const float* src;
    ushort* dst;
    if (gw < R) { src = x + (size_t)gw * D_;        dst = xb + (size_t)gw * D_; }
    else        { src = y + (size_t)(gw - R) * D_;  dst = yb + (size_t)(gw - R) * D_; }

    float4 v = reinterpret_cast<const float4*>(src)[lane];
    float ss = v.x * v.x + v.y * v.y + v.z * v.z + v.w * v.w;
#pragma unroll
    for (int off = 32; off; off >>= 1) ss += __shfl_xor(ss, off);
    float scale = ss > 0.f ? rsqrtf(ss) : 0.f;

    ushort4 o;
    o.x = f2bf(v.x * scale);
    o.y = f2bf(v.y * scale);
    o.z = f2bf(v.z * scale);
    o.w = f2bf(v.w * scale);
    reinterpret_cast<ushort4*>(dst)[lane] = o;
}

// C[b][m][n] = sum_d Yb[b][m][d] * Xb[b][n][d]
// Block: 128-row band x 1024 cols (8 col-tiles of 128), grid 512 = 2/CU resident.
// A (Y rows): k<128 in LDS (staged ONCE, swizzled), k>=128 in registers.
// B (X rows): double-buffered 16KB tiles, 4 global_load_lds per thread per step.
// 32 K-steps; R4-proven counted-vmcnt + sliced-store skeleton.
__global__ __launch_bounds__(256, 2) void cosgemm(const ushort* __restrict__ Xb,
                                                  const ushort* __restrict__ Yb,
                                                  float* __restrict__ out) {
    // LDS: [0,32K) A rows0..127 x k0..127 | [32K,48K) Bbuf0 | [48K,64K) Bbuf1
    __shared__ char smem[65536];

    const int tid  = threadIdx.x;
    const int w    = tid >> 6;
    const int lane = tid & 63;

    // XCD-aware bijective swizzle: 512 blocks, 8 XCDs, 64 per XCD chunk
    int bid = blockIdx.x;
    int swz = ((bid & 7) << 6) | (bid >> 3);
    int b   = swz >> 7;
    int t   = swz & 127;
    int tm  = (t >> 2) << 7;        // 32 row-bands
    int tno = (t & 3) << 10;        // 4 col-octs * 1024

    const ushort* Ag = Yb + ((size_t)b * M_ + tm) * D_;
    const ushort* Bg = Xb + ((size_t)b * N_ + tno) * D_;

    const int wr = (w >> 1) << 6;
    const int wc = (w & 1) << 6;

    // ---- prologue: stage A(k<128) to LDS once; chunk c = rows 4c..4c+3 (256B rows)
    // swizzle: LDS slot s of row r holds global slot s ^ (r&7); dest linear.
#pragma unroll
    for (int i = 0; i < 8; ++i) {
        int c = i * 4 + w;                               // 32 chunks of 1KB
        int gsA = (lane & 15) ^ (4 * (c & 1) + (lane >> 4));
        const ushort* ga = Ag + (size_t)(c * 4 + (lane >> 4)) * D_ + gsA * 8;
        __builtin_amdgcn_global_load_lds((const AS1 void*)ga,
                                         (AS3 void*)(smem + c * 1024), 16, 0, 0);
    }
    // A(k>=128) into registers
    bf16x8 areg[4][4];
#pragma unroll
    for (int m = 0; m < 4; ++m)
#pragma unroll
        for (int c4 = 0; c4 < 4; ++c4) {
            const ushort* ga = Ag + (size_t)(wr + m * 16 + (lane & 15)) * D_
                             + 128 + c4 * 32 + (lane >> 4) * 8;
            areg[m][c4] = *reinterpret_cast<const bf16x8*>(ga);
        }

    // B staging: chunk c = 8 rows (128B each); linear dest, inverse-swizzled source
    const int srow  = lane >> 3;
    const int gslot = (lane & 7) ^ srow;
    auto stageB = [&](int buf, int ct, int kc) {
        char* base = smem + 32768 + buf * 16384;
        const ushort* Bq = Bg + (size_t)(ct * 128) * D_ + kc * 64;
#pragma unroll
        for (int i = 0; i < 4; ++i) {
            int c = i * 4 + w;                           // 16 chunks of 1KB
            const ushort* gb = Bq + (size_t)(c * 8 + srow) * D_ + gslot * 8;
            __builtin_amdgcn_global_load_lds((const AS1 void*)gb,
                                             (AS3 void*)(base + c * 1024), 16, 0, 0);
        }
    };

    auto compute = [&](f32x4 (&acc)[4][4], int buf, int kc, bool zi) {
        const char* Bbase = smem + 32768 + buf * 16384;
        if (zi) {
#pragma unroll
            for (int m = 0; m < 4; ++m)
#pragma unroll
                for (int n = 0; n < 4; ++n)
                    acc[m][n] = (f32x4){0.f, 0.f, 0.f, 0.f};
        }
#pragma unroll
        for (int ks = 0; ks < 2; ++ks) {
            bf16x8 afr[4], bfr[4];
            if (kc < 2) {   // A from LDS: k = kc*64 + ks*32 + (lane>>4)*8
                const int colbA = ((kc * 8 + ks * 4 + (lane >> 4)) ^ (lane & 7)) << 4;
#pragma unroll
                for (int m = 0; m < 4; ++m) {
                    int row = wr + m * 16 + (lane & 15);
                    afr[m] = *reinterpret_cast<const bf16x8*>(smem + row * 256 + colbA);
                }
            } else {        // A from registers
#pragma unroll
                for (int m = 0; m < 4; ++m) afr[m] = areg[m][(kc - 2) * 2 + ks];
            }
            const int colb = ((ks * 4 + (lane >> 4)) ^ (lane & 7)) << 4;
#pragma unroll
            for (int n = 0; n < 4; ++n) {
                int row = wc + n * 16 + (lane & 15);
                bfr[n] = *reinterpret_cast<const bf16x8*>(Bbase + row * 128 + colb);
            }
#pragma unroll
            for (int m = 0; m < 4; ++m)
#pragma unroll
                for (int n = 0; n < 4; ++n)
                    acc[m][n] = __builtin_amdgcn_mfma_f32_16x16x32_bf16(
                        afr[m], bfr[n], acc[m][n], 0, 0, 0);
        }
    };

    // C/D layout: col = lane&15, row = (lane>>4)*4 + reg   [m89-verified]
    auto store_slice = [&](f32x4 (&acc)[4][4], int tn, int m) {
        const int rj = (lane >> 4) << 2;
        const int cj = lane & 15;
#pragma unroll
        for (int j = 0; j < 4; ++j) {
            size_t r = (size_t)(tm + wr + m * 16 + rj + j);
            float* rowp = out + ((size_t)b * M_ + r) * N_ + tn + wc + cj;
#pragma unroll
            for (int n = 0; n < 4; ++n)
                rowp[n * 16] = acc[m][n][j];
        }
    };

    f32x4 acc0[4][4], acc1[4][4];

    stageB(0, 0, 0);   // queue: [A_lds 8, areg 16 (compiler loads), stageB0 4]

#pragma unroll
    for (int s = 0; s < 32; ++s) {
        const int ct = s >> 2, kc = s & 3, buf = s & 1;
        __builtin_amdgcn_s_barrier();                   // buf^1 readers done
        if (s < 31) stageB(buf ^ 1, (s + 1) >> 2, (s + 1) & 3);
        // drain stage(s) (s=0: plus A-LDS/areg). Queue: [stage(s)4, slice16?, stage(s+1)4]
        if (s < 5)       asm volatile("s_waitcnt vmcnt(4)"  ::: "memory");
        else if (s < 31) asm volatile("s_waitcnt vmcnt(20)" ::: "memory");
        else             asm volatile("s_waitcnt vmcnt(16)" ::: "memory");
        __builtin_amdgcn_s_barrier();                   // buf[s] ready everywhere
        __builtin_amdgcn_sched_barrier(0);

        const bool zi = (kc == 0);
        if ((ct & 1) == 0) compute(acc0, buf, kc, zi);
        else               compute(acc1, buf, kc, zi);

        const int pq = ct - 1;   // slice kc of previous col-tile
        if (pq >= 0) {
            __builtin_amdgcn_sched_barrier(0);
            if ((pq & 1) == 0) store_slice(acc0, tno + pq * 128, kc);
            else               store_slice(acc1, tno + pq * 128, kc);
            __builtin_amdgcn_sched_barrier(0);
        }
    }

    // tail: col-tile 7 (odd -> acc1)
#pragma unroll
    for (int m = 0; m < 4; ++m)
        store_slice(acc1, tno + 7 * 128, m);
}

extern "C" void kernel_launch(void* const* d_in, const int* in_sizes, int n_in,
                              void* d_out, int out_size, void* d_ws, size_t ws_size,
                              hipStream_t stream) {
    const float* x = (const float*)d_in[0];   // [4,4096,256] f32
    const float* y = (const float*)d_in[1];   // [4,4096,256] f32
    float* out = (float*)d_out;               // [4,4096,4096] f32

    ushort* xb = (ushort*)d_ws;                       // bf16 normalized x
    ushort* yb = xb + (size_t)B_ * N_ * D_;           // bf16 normalized y

    norm_cvt<<<8192, 256, 0, stream>>>(x, y, xb, yb); // 32768 rows, 4 waves/block
    cosgemm<<<512, 256, 0, stream>>>(xb, yb, out);    // 4 batches * 32 bands * 4 octs
}